// Round 2
// baseline (12253.903 us; speedup 1.0000x reference)
//
#include <hip/hip_runtime.h>

// Conv 3x3 SAME, stride 1, C=16 -> O=16, fp32.
// Input viewed as NHWC via raw reshape of NCHW buffer:
//   x[b,h,w,c] = flat[b*16777216 + (h*1024 + w)*16 + c]
// Weight HWIO: w[kh,kw,c,o] = flat[((kh*3+kw)*16 + c)*16 + o]
// Output NCHW: out[b,o,h,w] = flat[((b*16+o)*1024 + h)*1024 + w]
//
// V3 changes vs V2 (850 us/dispatch, VALUBusy 43%, occupancy 22%):
//  - V2 fixed the spill traffic (FETCH/WRITE now exactly input/output size)
//    but stayed latency-bound: 57% VALU-idle, occupancy pinned at ~2
//    waves/SIMD (tracks the __launch_bounds__(256,2) 2nd arg).
//  - Software-pipeline the 12 flattened (kh,cb) stages ping-pong style:
//    issue stage s+1's 6 global loads, then run stage s's 768 FMAs
//    (~1536 cyc of cover >> 900-cyc HBM latency) -> loads hidden even at
//    low occupancy. Named xA/xB buffers, unroll-by-2 (runtime-indexed
//    arrays would go to scratch).
//  - __launch_bounds__(256, 4): lift the waves/EU floor, keep VGPR <= 128.

constexpr int Hs = 1024, Ws = 1024, Cs = 16, Os = 16;

__device__ __forceinline__ float f4c(const float4 v, int cl) {
    // cl is compile-time after full unroll
    return cl == 0 ? v.x : cl == 1 ? v.y : cl == 2 ? v.z : v.w;
}

__global__ __launch_bounds__(256, 4)
void conv3x3_c16o16(const float* __restrict__ x,
                    const float* __restrict__ wgt,
                    float* __restrict__ out)
{
    __shared__ float lw[3 * 3 * Cs * Os];   // 2304 floats = 9 KB
    const int t = threadIdx.x;
    #pragma unroll
    for (int i = 0; i < 9; ++i) lw[t + 256 * i] = wgt[t + 256 * i];
    __syncthreads();

    // XCD swizzle: grid = 8192 = 8 batches x 1024 rows; raw%8 = XCD under
    // round-robin dispatch -> each XCD owns one batch, rows in order, so the
    // h+-1 halo rows hit the same XCD's L2.
    const int raw = (int)blockIdx.x;
    const int b   = raw & 7;
    const int h   = raw >> 3;
    const int w0  = t << 2;              // 4 pixels per thread, full row per block

    const float* xb = x + (size_t)b * ((size_t)Hs * Ws * Cs);

    float acc[4][16];
    #pragma unroll
    for (int p = 0; p < 4; ++p)
        #pragma unroll
        for (int o = 0; o < 16; ++o) acc[p][o] = 0.f;

    // Stage s = kh*4 + cb, s in [0,12). Each stage: 6 input pixels
    // (w0-1..w0+4) x 4 channels (cb*4..cb*4+3) = 6 float4 = 24 VGPRs.
    auto LOAD = [&](int s, float4 (&xr)[6]) {
        const int kh = s >> 2, cb = s & 3;
        const int hh = h - 1 + kh;
        const bool rowv = (hh >= 0) && (hh < Hs);
        const float* xrow = xb + (size_t)hh * ((size_t)Ws * Cs) + cb * 4;
        #pragma unroll
        for (int j = 0; j < 6; ++j) {
            const int ww = w0 - 1 + j;
            const bool v = rowv && (ww >= 0) && (ww < Ws);
            xr[j] = v ? *(const float4*)(xrow + (size_t)ww * Cs)
                      : make_float4(0.f, 0.f, 0.f, 0.f);
        }
    };

    // 4 channels x 3 kw x 16 o x 4 px = 768 FMAs per stage.
    auto COMP = [&](int s, const float4 (&xr)[6]) {
        const int kh = s >> 2, cb = s & 3;
        #pragma unroll
        for (int cl = 0; cl < 4; ++cl) {
            const int c = cb * 4 + cl;
            #pragma unroll
            for (int kw = 0; kw < 3; ++kw) {
                // 16 output-channel weights: broadcast ds_read_b128 x4,
                // amortized over 4 pixels -> 16 FMA per ds_read_b128.
                const float* wp = &lw[((kh * 3 + kw) * Cs + c) * Os];
                #pragma unroll
                for (int q = 0; q < 4; ++q) {
                    const float4 wq = ((const float4*)wp)[q];
                    #pragma unroll
                    for (int p = 0; p < 4; ++p) {
                        const float xv = f4c(xr[p + kw], cl);
                        acc[p][4 * q + 0] = fmaf(xv, wq.x, acc[p][4 * q + 0]);
                        acc[p][4 * q + 1] = fmaf(xv, wq.y, acc[p][4 * q + 1]);
                        acc[p][4 * q + 2] = fmaf(xv, wq.z, acc[p][4 * q + 2]);
                        acc[p][4 * q + 3] = fmaf(xv, wq.w, acc[p][4 * q + 3]);
                    }
                }
            }
        }
    };

    // Ping-pong software pipeline: loads for stage s+1 issue before the
    // FMAs of stage s consume xA -> ~1536 cycles of compute cover per
    // 6-load batch. Explicit A/B names keep all indexing compile-time.
    float4 xA[6], xB[6];
    LOAD(0, xA);
    #pragma unroll 1                      // keep body ~2 stages, I$-safe
    for (int s = 0; s < 12; s += 2) {
        LOAD(s + 1, xB);
        COMP(s, xA);
        if (s + 2 < 12) LOAD(s + 2, xA);
        COMP(s + 1, xB);
    }

    // store: NCHW, float4 along w per output plane (coalesced)
    float* ob = out + (((size_t)b * Os) * Hs + (size_t)h) * Ws + w0;
    #pragma unroll
    for (int o = 0; o < 16; ++o) {
        float4 st = make_float4(acc[0][o], acc[1][o], acc[2][o], acc[3][o]);
        *(float4*)(ob + (size_t)o * (Hs * Ws)) = st;
    }
}

extern "C" void kernel_launch(void* const* d_in, const int* in_sizes, int n_in,
                              void* d_out, int out_size, void* d_ws, size_t ws_size,
                              hipStream_t stream)
{
    const float* x   = (const float*)d_in[0];
    const float* wgt = (const float*)d_in[1];
    float* out       = (float*)d_out;

    dim3 grid(8 * Hs);   // one block per (b, h) row
    dim3 block(256);
    conv3x3_c16o16<<<grid, block, 0, stream>>>(x, wgt, out);
}

// Round 3
// 2603.826 us; speedup vs baseline: 4.7061x; 4.7061x over previous
//
#include <hip/hip_runtime.h>

// Conv 3x3 SAME, stride 1, C=16 -> O=16, fp32.
// Input viewed as NHWC via raw reshape of NCHW buffer:
//   x[b,h,w,c] = flat[b*16777216 + (h*1024 + w)*16 + c]
// Weight HWIO: w[kh,kw,c,o] = flat[((kh*3+kw)*16 + c)*16 + o]
// Output NCHW: out[b,o,h,w] = flat[((b*16+o)*1024 + h)*1024 + w]
//
// V4 changes vs V2 (850 us/dispatch, VALUBusy 43%) and V3 (spill disaster):
//  - V3 lesson: __launch_bounds__ 2nd arg 4 drove the allocator to the
//    64-VGPR bucket and it spilled acc[] -> 26 GB scratch writes. Reverted
//    to (256,2) which gave 100 VGPR / zero spill in V2.
//  - V2 lesson (counter arithmetic): 576 ds_read_b128/thread for weights =
//    27.6k LDS-pipe cycles per 4-wave block vs only 18.4k VALU cycles.
//    The CU's single LDS pipe was the bottleneck, serialized against FMAs
//    (VALUBusy 43% == predicted LDS-bound fraction 43%).
//  - Fix: NO LDS AT ALL. Weight addresses are wave-uniform -> read straight
//    from global; hipcc uniformity analysis emits s_load into SGPRs through
//    the scalar pipe / K$ (9 KB, L2-resident, reread per block is free).
//    v_fma_f32 takes 1 SGPR operand -> FMAs read weights from SGPRs.

constexpr int Hs = 1024, Ws = 1024, Cs = 16, Os = 16;

__device__ __forceinline__ float f4c(const float4 v, int cl) {
    // cl is compile-time after full unroll
    return cl == 0 ? v.x : cl == 1 ? v.y : cl == 2 ? v.z : v.w;
}

__global__ __launch_bounds__(256, 2)
void conv3x3_c16o16(const float* __restrict__ x,
                    const float* __restrict__ wgt,
                    float* __restrict__ out)
{
    const int t = threadIdx.x;

    // XCD swizzle: grid = 8192 = 8 batches x 1024 rows; raw%8 = XCD under
    // round-robin dispatch -> each XCD owns one batch, rows in order, so the
    // h+-1 halo rows hit the same XCD's L2.
    const int raw = (int)blockIdx.x;
    const int b   = raw & 7;
    const int h   = raw >> 3;
    const int w0  = t << 2;              // 4 pixels per thread, full row per block

    const float* xb = x + (size_t)b * ((size_t)Hs * Ws * Cs);

    float acc[4][16];
    #pragma unroll
    for (int p = 0; p < 4; ++p)
        #pragma unroll
        for (int o = 0; o < 16; ++o) acc[p][o] = 0.f;

    #pragma unroll 1                      // runtime kh loop: keep body small
    for (int kh = 0; kh < 3; ++kh) {
        const int hh = h - 1 + kh;
        if (hh < 0 || hh >= Hs) continue; // block-uniform branch (zero pad)
        const float* xrow = xb + (size_t)hh * ((size_t)Ws * Cs);
        const float* wk   = wgt + kh * (3 * Cs * Os);   // uniform base

        #pragma unroll 1                  // runtime cb loop: ~7 KB body, I$-safe
        for (int cb = 0; cb < 4; ++cb) {
            // 6 input pixels (w0-1 .. w0+4) x 4 channels -> 24 VGPRs.
            float4 xr[6];
            #pragma unroll
            for (int j = 0; j < 6; ++j) {
                const int ww = w0 - 1 + j;
                const bool v = (ww >= 0) && (ww < Ws);
                xr[j] = v ? *(const float4*)(xrow + (size_t)ww * Cs + cb * 4)
                          : make_float4(0.f, 0.f, 0.f, 0.f);
            }

            #pragma unroll
            for (int cl = 0; cl < 4; ++cl) {
                const int c = cb * 4 + cl;
                #pragma unroll
                for (int kw = 0; kw < 3; ++kw) {
                    // Wave-uniform weight pointer: compiler emits scalar
                    // loads (s_load_dwordx4) -> weights live in SGPRs,
                    // zero LDS/vector-memory cost in the FMA loop.
                    const float* wp = wk + ((size_t)kw * Cs + c) * Os;
                    #pragma unroll
                    for (int q = 0; q < 4; ++q) {
                        const float4 wq = ((const float4*)wp)[q];
                        #pragma unroll
                        for (int p = 0; p < 4; ++p) {
                            const float xv = f4c(xr[p + kw], cl);
                            acc[p][4 * q + 0] = fmaf(xv, wq.x, acc[p][4 * q + 0]);
                            acc[p][4 * q + 1] = fmaf(xv, wq.y, acc[p][4 * q + 1]);
                            acc[p][4 * q + 2] = fmaf(xv, wq.z, acc[p][4 * q + 2]);
                            acc[p][4 * q + 3] = fmaf(xv, wq.w, acc[p][4 * q + 3]);
                        }
                    }
                }
            }
        }
    }

    // store: NCHW, float4 along w per output plane (coalesced)
    float* ob = out + (((size_t)b * Os) * Hs + (size_t)h) * Ws + w0;
    #pragma unroll
    for (int o = 0; o < 16; ++o) {
        float4 st = make_float4(acc[0][o], acc[1][o], acc[2][o], acc[3][o]);
        *(float4*)(ob + (size_t)o * (Hs * Ws)) = st;
    }
}

extern "C" void kernel_launch(void* const* d_in, const int* in_sizes, int n_in,
                              void* d_out, int out_size, void* d_ws, size_t ws_size,
                              hipStream_t stream)
{
    const float* x   = (const float*)d_in[0];
    const float* wgt = (const float*)d_in[1];
    float* out       = (float*)d_out;

    dim3 grid(8 * Hs);   // one block per (b, h) row
    dim3 block(256);
    conv3x3_c16o16<<<grid, block, 0, stream>>>(x, wgt, out);
}